// Round 1
// baseline (399.500 us; speedup 1.0000x reference)
//
#include <hip/hip_runtime.h>
#include <stdint.h>

typedef uint32_t u32;
typedef short s16x8 __attribute__((ext_vector_type(8)));
typedef float f32x16 __attribute__((ext_vector_type(16)));
typedef u32 u32x4 __attribute__((ext_vector_type(4)));

#define NPIX   262144
#define HD     256
#define PEDIM  54
#define NTHR   512

// LDS layout: actA [256 rows][256 cols] bf16, swizzled  -> 131072 B
//             wbuf W k-slice [256 col][64 k] bf16, swizzled -> 32768 B
#define ACT_BYTES 131072
#define LDS_BYTES 163840

__device__ __forceinline__ u32 bfpair(float a, float b) {
    u32 ua = __builtin_bit_cast(u32, a);
    u32 ub = __builtin_bit_cast(u32, b);
    ua = (ua + 0x7FFFu + ((ua >> 16) & 1u)) >> 16;
    ub = (ub + 0x7FFFu + ((ub >> 16) & 1u)) >> 16;
    return ua | (ub << 16);
}
__device__ __forceinline__ uint16_t f2bf(float x) {
    u32 u = __builtin_bit_cast(u32, x);
    u = (u + 0x7FFFu + ((u >> 16) & 1u)) >> 16;
    return (uint16_t)u;
}
// byte offset into actA: row stride 512B, XOR-swizzle bits 4-6 by row&7
__device__ __forceinline__ u32 act_off(int row, int colByte) {
    return (u32)((row << 9) + (colByte ^ ((row & 7) << 4)));
}
// byte offset into wbuf: col stride 128B (64 k * 2B), XOR-swizzle bits 4-6 by col&7
__device__ __forceinline__ u32 w_off(int col, int kByte) {
    return (u32)((col << 7) + (kByte ^ ((col & 7) << 4)));
}

extern "C" __global__ __launch_bounds__(NTHR, 2)
void loe_fused(const float* __restrict__ coords,
               const float* __restrict__ w0, const float* __restrict__ b0,
               const float* __restrict__ w1, const float* __restrict__ b1,
               const float* __restrict__ w2, const float* __restrict__ b2,
               const float* __restrict__ w3, const float* __restrict__ b3,
               const float* __restrict__ w4, const float* __restrict__ b4,
               const float* __restrict__ wl, const float* __restrict__ bl,
               float* __restrict__ out)
{
    extern __shared__ char lds[];
    char* wb = lds + ACT_BYTES;

    const int tid  = threadIdx.x;
    const int lane = tid & 63;
    const int wv   = tid >> 6;      // wave 0..7
    const int wr   = wv >> 2;       // row-group 0..1 (128 rows each)
    const int wc   = wv & 3;        // col-group 0..3 (64 cols each)
    const int l31  = lane & 31;
    const int lhi  = lane >> 5;     // 0/1

    const int bid  = (int)blockIdx.x;
    // XCD-chunked swizzle (bijective, 1024 = 8*128): neighbors share L2-resident W tiles
    const int pb   = ((bid & 7) << 7) | (bid >> 3);
    const int pix0 = pb << 8;

    // ---------------- positional encoding -> actA[256][64] ----------------
    {
        const int p = tid >> 1;
        const int h = tid & 1;
        const float2 c2 = reinterpret_cast<const float2*>(coords)[pix0 + p];
        const float cf[2] = {c2.x, c2.y};
        #pragma unroll
        for (int u = 0; u < 32; u += 2) {
            float v[2];
            #pragma unroll
            for (int q = 0; q < 2; ++q) {
                const int c = h * 32 + u + q;
                float val;
                if (c < 2) {
                    val = cf[c];
                } else if (c - 2 >= 52) {
                    val = 0.0f;                      // pad cols 54..63
                } else {
                    const int e = c - 2;
                    const int fi = e >> 2;
                    const int fj = (e >> 1) & 1;
                    const float a = cf[fj] * (float)(1 << fi);  // exact pow2 scale
                    val = (e & 1) ? cospif(a) : sinpif(a);      // sin/cos(2^i * pi * c)
                }
                v[q] = val;
            }
            const int c0 = h * 32 + u;
            *reinterpret_cast<u32*>(lds + act_off(p, c0 * 2)) = bfpair(v[0], v[1]);
        }
    }

    // ---------------- stage layer-0 W (54x256, pad K to 64) ----------------
    {
        const int scol = tid & 255;
        const int kg0  = tid >> 8;     // 0..1
        #pragma unroll
        for (int rep = 0; rep < 4; ++rep) {
            const int kg = kg0 + rep * 2;          // 0..7
            float v[8];
            #pragma unroll
            for (int j = 0; j < 8; ++j) {
                const int k = kg * 8 + j;
                v[j] = (k < PEDIM) ? w0[k * HD + scol] : 0.0f;
            }
            u32x4 pk;
            pk.x = bfpair(v[0], v[1]); pk.y = bfpair(v[2], v[3]);
            pk.z = bfpair(v[4], v[5]); pk.w = bfpair(v[6], v[7]);
            *reinterpret_cast<u32x4*>(wb + w_off(scol, kg * 16)) = pk;
        }
    }
    __syncthreads();

    f32x16 acc[4][2];

    // epilogue: acc -> LeakyReLU -> bf16 -> actA (swizzled scalar u16 writes)
    auto write_act = [&]() {
        #pragma unroll
        for (int mt = 0; mt < 4; ++mt)
            #pragma unroll
            for (int nt = 0; nt < 2; ++nt) {
                const int col = wc * 64 + nt * 32 + l31;
                #pragma unroll
                for (int r = 0; r < 16; ++r) {
                    float x = acc[mt][nt][r];
                    x = (x > 0.0f) ? x : 0.2f * x;
                    const int row = wr * 128 + mt * 32 + (r & 3) + ((r >> 2) << 3) + (lhi << 2);
                    *reinterpret_cast<uint16_t*>(lds + act_off(row, col * 2)) = f2bf(x);
                }
            }
    };

    // ---------------- layer 0: [256x64] x [64x256] ----------------
    {
        float bias[2] = { b0[wc * 64 + l31], b0[wc * 64 + 32 + l31] };
        #pragma unroll
        for (int mt = 0; mt < 4; ++mt)
            #pragma unroll
            for (int nt = 0; nt < 2; ++nt)
                #pragma unroll
                for (int r = 0; r < 16; ++r)
                    acc[mt][nt][r] = bias[nt];
        #pragma unroll
        for (int kt = 0; kt < 4; ++kt) {
            const int kb = kt * 32 + lhi * 16;
            s16x8 bfr[2], afr[4];
            #pragma unroll
            for (int nt = 0; nt < 2; ++nt)
                bfr[nt] = *reinterpret_cast<const s16x8*>(wb + w_off(wc * 64 + nt * 32 + l31, kb));
            #pragma unroll
            for (int mt = 0; mt < 4; ++mt)
                afr[mt] = *reinterpret_cast<const s16x8*>(lds + act_off(wr * 128 + mt * 32 + l31, kb));
            #pragma unroll
            for (int mt = 0; mt < 4; ++mt)
                #pragma unroll
                for (int nt = 0; nt < 2; ++nt)
                    acc[mt][nt] = __builtin_amdgcn_mfma_f32_32x32x16_bf16(afr[mt], bfr[nt], acc[mt][nt], 0, 0, 0);
        }
    }
    __syncthreads();
    write_act();

    // ---------------- hidden layers 1..4: [256x256] x [256x256] ----------------
    const float* Wt[4] = { w1 + (size_t)(pb >> 8) * 65536, w2 + (size_t)(pb >> 6) * 65536,
                           w3 + (size_t)(pb >> 4) * 65536, w4 + (size_t)(pb >> 2) * 65536 };
    const float* Bt[4] = { b1, b2, b3, b4 };

    const int scol = tid & 255;
    const int kg0  = tid >> 8;

    for (int L = 0; L < 4; ++L) {
        const float* W = Wt[L];
        float bias[2] = { Bt[L][wc * 64 + l31], Bt[L][wc * 64 + 32 + l31] };
        #pragma unroll
        for (int mt = 0; mt < 4; ++mt)
            #pragma unroll
            for (int nt = 0; nt < 2; ++nt)
                #pragma unroll
                for (int r = 0; r < 16; ++r)
                    acc[mt][nt][r] = bias[nt];

        float st[4][8];
        // prefetch k-slice 0 into registers
        #pragma unroll
        for (int rep = 0; rep < 4; ++rep) {
            const int kg = kg0 + rep * 2;
            const float* src = W + (size_t)(kg * 8) * HD + scol;
            #pragma unroll
            for (int j = 0; j < 8; ++j) st[rep][j] = src[j * HD];
        }

        for (int s = 0; s < 4; ++s) {
            __syncthreads();                       // prev readers of wbuf done
            #pragma unroll
            for (int rep = 0; rep < 4; ++rep) {    // regs -> bf16 -> wbuf (transposed)
                const int kg = kg0 + rep * 2;
                u32x4 pk;
                pk.x = bfpair(st[rep][0], st[rep][1]);
                pk.y = bfpair(st[rep][2], st[rep][3]);
                pk.z = bfpair(st[rep][4], st[rep][5]);
                pk.w = bfpair(st[rep][6], st[rep][7]);
                *reinterpret_cast<u32x4*>(wb + w_off(scol, kg * 16)) = pk;
            }
            if (s < 3) {                           // issue next-slice loads; latency hides under MFMA
                #pragma unroll
                for (int rep = 0; rep < 4; ++rep) {
                    const int kg = kg0 + rep * 2;
                    const float* src = W + (size_t)((s + 1) * 64 + kg * 8) * HD + scol;
                    #pragma unroll
                    for (int j = 0; j < 8; ++j) st[rep][j] = src[j * HD];
                }
            }
            __syncthreads();                       // wbuf (and, at s=0, actA) ready
            #pragma unroll
            for (int kt = 0; kt < 4; ++kt) {
                const int kb = kt * 32 + lhi * 16;
                s16x8 bfr[2], afr[4];
                #pragma unroll
                for (int nt = 0; nt < 2; ++nt)
                    bfr[nt] = *reinterpret_cast<const s16x8*>(wb + w_off(wc * 64 + nt * 32 + l31, kb));
                #pragma unroll
                for (int mt = 0; mt < 4; ++mt)
                    afr[mt] = *reinterpret_cast<const s16x8*>(lds + act_off(wr * 128 + mt * 32 + l31, s * 128 + kb));
                #pragma unroll
                for (int mt = 0; mt < 4; ++mt)
                    #pragma unroll
                    for (int nt = 0; nt < 2; ++nt)
                        acc[mt][nt] = __builtin_amdgcn_mfma_f32_32x32x16_bf16(afr[mt], bfr[nt], acc[mt][nt], 0, 0, 0);
            }
        }
        __syncthreads();
        write_act();
    }

    // ---------------- head: [256x256] x [256x3] ----------------
    // stage w_last^T zero-padded to 32 cols: layout [32 col][256 k] bf16, 512B rows, same swizzle family
    #pragma unroll
    for (int rep = 0; rep < 2; ++rep) {
        const int task = rep * NTHR + tid;     // 0..1023
        const int col  = task & 31;
        const int kg   = task >> 5;            // 0..31
        float v[8];
        #pragma unroll
        for (int j = 0; j < 8; ++j)
            v[j] = (col < 3) ? wl[col * HD + kg * 8 + j] : 0.0f;
        u32x4 pk;
        pk.x = bfpair(v[0], v[1]); pk.y = bfpair(v[2], v[3]);
        pk.z = bfpair(v[4], v[5]); pk.w = bfpair(v[6], v[7]);
        *reinterpret_cast<u32x4*>(wb + (col * 512 + ((kg * 16) ^ ((col & 7) << 4)))) = pk;
    }
    __syncthreads();

    {
        const int col = l31;                   // output channel (0..2 live)
        const float blv = (col < 3) ? bl[col] : 0.0f;
        f32x16 accF;
        #pragma unroll
        for (int r = 0; r < 16; ++r) accF[r] = blv;
        #pragma unroll
        for (int kt = 0; kt < 16; ++kt) {
            const int kb = kt * 32 + lhi * 16;
            s16x8 a = *reinterpret_cast<const s16x8*>(lds + act_off(wv * 32 + l31, kb));
            s16x8 b = *reinterpret_cast<const s16x8*>(wb + (col * 512 + (kb ^ ((col & 7) << 4))));
            accF = __builtin_amdgcn_mfma_f32_32x32x16_bf16(a, b, accF, 0, 0, 0);
        }
        if (col < 3) {
            #pragma unroll
            for (int r = 0; r < 16; ++r) {
                const int row = (r & 3) + ((r >> 2) << 3) + (lhi << 2);
                out[(size_t)(pix0 + wv * 32 + row) * 3 + col] = accF[r];
            }
        }
    }
}

extern "C" void kernel_launch(void* const* d_in, const int* in_sizes, int n_in,
                              void* d_out, int out_size, void* d_ws, size_t ws_size,
                              hipStream_t stream) {
    (void)in_sizes; (void)n_in; (void)d_ws; (void)ws_size; (void)out_size;
    const float* coords = (const float*)d_in[0];
    const float* w0 = (const float*)d_in[1];  const float* b0 = (const float*)d_in[2];
    const float* w1 = (const float*)d_in[3];  const float* b1 = (const float*)d_in[4];
    const float* w2 = (const float*)d_in[5];  const float* b2 = (const float*)d_in[6];
    const float* w3 = (const float*)d_in[7];  const float* b3 = (const float*)d_in[8];
    const float* w4 = (const float*)d_in[9];  const float* b4 = (const float*)d_in[10];
    const float* wl = (const float*)d_in[11]; const float* bl = (const float*)d_in[12];
    float* out = (float*)d_out;

    hipFuncSetAttribute((const void*)loe_fused,
                        hipFuncAttributeMaxDynamicSharedMemorySize, LDS_BYTES);

    loe_fused<<<dim3(NPIX / 256), dim3(NTHR), LDS_BYTES, stream>>>(
        coords, w0, b0, w1, b1, w2, b2, w3, b3, w4, b4, wl, bl, out);
}

// Round 2
// 221.796 us; speedup vs baseline: 1.8012x; 1.8012x over previous
//
#include <hip/hip_runtime.h>
#include <stdint.h>

typedef uint32_t u32;
typedef short s16x8 __attribute__((ext_vector_type(8)));
typedef float f32x16 __attribute__((ext_vector_type(16)));
typedef u32 u32x2 __attribute__((ext_vector_type(2)));
typedef u32 u32x4 __attribute__((ext_vector_type(4)));

#define NPIX   262144
#define HD     256
#define NTHR   512

// LDS: actA [256 rows][256 cols] bf16 swizzled (128KB) + 2x wbuf [256 col][32 k] bf16 (16KB each)
#define ACT_BYTES  131072
#define WBUF_BYTES 16384
#define LDS_BYTES  (ACT_BYTES + 2 * WBUF_BYTES)   // 163840 = 160 KiB exactly

__device__ __forceinline__ u32 bfpair(float a, float b) {
    u32 ua = __builtin_bit_cast(u32, a);
    u32 ub = __builtin_bit_cast(u32, b);
    ua = (ua + 0x7FFFu + ((ua >> 16) & 1u)) >> 16;
    ub = (ub + 0x7FFFu + ((ub >> 16) & 1u)) >> 16;
    return ua | (ub << 16);
}
// actA: row stride 512B, XOR-swizzle byte bits 4-6 by row&7
__device__ __forceinline__ u32 act_off(int row, int colByte) {
    return (u32)((row << 9) + (colByte ^ ((row & 7) << 4)));
}
// wbuf: col stride 64B (32 k * 2B), XOR-swizzle byte bits 4-5 by (col>>1)&3
__device__ __forceinline__ u32 w_off32(int col, int kByte) {
    return (u32)((col << 6) + (kByte ^ (((col >> 1) & 3) << 4)));
}

extern "C" __global__ __launch_bounds__(NTHR, 2)
void loe_fused(const float* __restrict__ coords,
               const float* __restrict__ w0, const float* __restrict__ b0,
               const float* __restrict__ w1, const float* __restrict__ b1,
               const float* __restrict__ w2, const float* __restrict__ b2,
               const float* __restrict__ w3, const float* __restrict__ b3,
               const float* __restrict__ w4, const float* __restrict__ b4,
               const float* __restrict__ wl, const float* __restrict__ bl,
               float* __restrict__ out)
{
    extern __shared__ char lds[];

    const int tid  = threadIdx.x;
    const int lane = tid & 63;
    const int wv   = tid >> 6;      // wave 0..7
    const int wr   = wv >> 2;       // pixel-half 0..1 (128 rows)
    const int wc   = wv & 3;        // feature-quarter 0..3 (64 cols)
    const int l31  = lane & 31;
    const int lhi  = lane >> 5;

    const int bid  = (int)blockIdx.x;
    const int pb   = ((bid & 7) << 7) | (bid >> 3);   // bijective XCD swizzle (1024 = 8*128)
    const int pix0 = pb << 8;

    const int scol = tid & 255;     // staging: feature column
    const int kh   = tid >> 8;      // staging: k half (16 k each)

    float st[16];

    auto load_plain = [&](const float* W, int s) {
        const float* src = W + (size_t)(s * 32 + kh * 16) * HD + scol;
        #pragma unroll
        for (int j = 0; j < 16; ++j) st[j] = src[(size_t)j * HD];
    };
    auto load_guard = [&](const float* W, int s) {   // layer-0: K=54 padded to 64
        #pragma unroll
        for (int j = 0; j < 16; ++j) {
            const int k = s * 32 + kh * 16 + j;
            st[j] = (k < 54) ? W[k * HD + scol] : 0.0f;
        }
    };

    // issue layer-0 slice-0 W loads first; they complete under the PE transcendentals
    load_guard(w0, 0);

    // ---------------- positional encoding -> actA[256][0..63] ----------------
    {
        const int p = tid >> 1;
        const int h = tid & 1;
        const float2 c2 = reinterpret_cast<const float2*>(coords)[pix0 + p];
        const float cf[2] = {c2.x, c2.y};
        #pragma unroll
        for (int u = 0; u < 32; u += 2) {
            float v[2];
            #pragma unroll
            for (int q = 0; q < 2; ++q) {
                const int c = h * 32 + u + q;
                float val;
                if (c < 2) {
                    val = cf[c];
                } else if (c - 2 >= 52) {
                    val = 0.0f;
                } else {
                    const int e = c - 2;
                    const int fi = e >> 2;
                    const int fj = (e >> 1) & 1;
                    const float a = cf[fj] * (float)(1 << fi);
                    val = (e & 1) ? cospif(a) : sinpif(a);
                }
                v[q] = val;
            }
            const int c0 = h * 32 + u;
            *reinterpret_cast<u32*>(lds + act_off(p, c0 * 2)) = bfpair(v[0], v[1]);
        }
    }

    f32x16 acc[4][2];   // swapped layout: acc[pixel-block][feature-block]; D row=feature, col=pixel
    int g = 0;          // global stage counter (wbuf parity)

    auto epilogue = [&](const float* Bias) {
        #pragma unroll
        for (int ct = 0; ct < 2; ++ct) {
            #pragma unroll
            for (int q = 0; q < 4; ++q) {
                const int oc0 = wc * 64 + ct * 32 + q * 8 + lhi * 4;
                const float4 bv = *reinterpret_cast<const float4*>(Bias + oc0);
                const float bj[4] = {bv.x, bv.y, bv.z, bv.w};
                #pragma unroll
                for (int pt = 0; pt < 4; ++pt) {
                    const int p = wr * 128 + pt * 32 + l31;
                    float x[4];
                    #pragma unroll
                    for (int j = 0; j < 4; ++j) {
                        float v = acc[pt][ct][q * 4 + j] + bj[j];
                        x[j] = (v > 0.0f) ? v : 0.2f * v;
                    }
                    u32x2 wv2;
                    wv2.x = bfpair(x[0], x[1]);
                    wv2.y = bfpair(x[2], x[3]);
                    *reinterpret_cast<u32x2*>(lds + act_off(p, oc0 * 2)) = wv2;
                }
            }
        }
    };

    auto run_layer = [&](int S, const float* Wcur, const float* Wnext,
                         const float* Bias, bool guard) {
        #pragma unroll
        for (int pt = 0; pt < 4; ++pt)
            #pragma unroll
            for (int ct = 0; ct < 2; ++ct)
                #pragma unroll
                for (int r = 0; r < 16; ++r) acc[pt][ct][r] = 0.0f;

        for (int s = 0; s < S; ++s) {
            char* wbw = lds + ACT_BYTES + ((g & 1) ? WBUF_BYTES : 0);
            // pack staged regs -> bf16 -> wbuf (transposed [col][k])
            u32x4 pk0, pk1;
            pk0.x = bfpair(st[0], st[1]);   pk0.y = bfpair(st[2], st[3]);
            pk0.z = bfpair(st[4], st[5]);   pk0.w = bfpair(st[6], st[7]);
            pk1.x = bfpair(st[8], st[9]);   pk1.y = bfpair(st[10], st[11]);
            pk1.z = bfpair(st[12], st[13]); pk1.w = bfpair(st[14], st[15]);
            *reinterpret_cast<u32x4*>(wbw + w_off32(scol, kh * 32))      = pk0;
            *reinterpret_cast<u32x4*>(wbw + w_off32(scol, kh * 32 + 16)) = pk1;
            // prefetch next k-slice (or next layer's slice 0); lands during MFMA below
            if (s + 1 < S) {
                if (guard) load_guard(Wcur, s + 1);
                else       load_plain(Wcur, s + 1);
            } else if (Wnext) {
                load_plain(Wnext, 0);
            }
            __syncthreads();
            const int kbase = s * 64;   // byte offset of this k-slice in act rows
            #pragma unroll
            for (int kt = 0; kt < 2; ++kt) {
                const int kb = kt * 32 + lhi * 16;
                s16x8 wf[2], af[4];
                #pragma unroll
                for (int ct = 0; ct < 2; ++ct)
                    wf[ct] = *reinterpret_cast<const s16x8*>(wbw + w_off32(wc * 64 + ct * 32 + l31, kb));
                #pragma unroll
                for (int pt = 0; pt < 4; ++pt)
                    af[pt] = *reinterpret_cast<const s16x8*>(lds + act_off(wr * 128 + pt * 32 + l31, kbase + kb));
                #pragma unroll
                for (int pt = 0; pt < 4; ++pt)
                    #pragma unroll
                    for (int ct = 0; ct < 2; ++ct)
                        acc[pt][ct] = __builtin_amdgcn_mfma_f32_32x32x16_bf16(wf[ct], af[pt], acc[pt][ct], 0, 0, 0);
            }
            ++g;
        }
        __syncthreads();   // all act reads done before overwrite
        epilogue(Bias);
    };

    const float* w1t = w1 + (size_t)(pb >> 8) * 65536;
    const float* w2t = w2 + (size_t)(pb >> 6) * 65536;
    const float* w3t = w3 + (size_t)(pb >> 4) * 65536;
    const float* w4t = w4 + (size_t)(pb >> 2) * 65536;

    run_layer(2, w0,  w1t, b0, true);
    run_layer(8, w1t, w2t, b1, false);
    run_layer(8, w2t, w3t, b2, false);
    run_layer(8, w3t, w4t, b3, false);
    run_layer(8, w4t, nullptr, b4, false);

    // ---------------- head: stage w_last^T [32 ch][256 k] into wbuf0 ----------------
    char* hw = lds + ACT_BYTES;
    #pragma unroll
    for (int rep = 0; rep < 2; ++rep) {
        const int task = rep * NTHR + tid;     // 0..1023
        const int col  = task & 31;
        const int kg   = task >> 5;            // 0..31 (8 k each)
        float v[8];
        #pragma unroll
        for (int j = 0; j < 8; ++j)
            v[j] = (col < 3) ? wl[col * HD + kg * 8 + j] : 0.0f;
        u32x4 pk;
        pk.x = bfpair(v[0], v[1]); pk.y = bfpair(v[2], v[3]);
        pk.z = bfpair(v[4], v[5]); pk.w = bfpair(v[6], v[7]);
        *reinterpret_cast<u32x4*>(hw + col * 512 + ((kg * 16) ^ ((col & 7) << 4))) = pk;
    }
    __syncthreads();   // act epilogue + head staging visible

    {
        f32x16 a;
        #pragma unroll
        for (int r = 0; r < 16; ++r) a[r] = 0.0f;
        #pragma unroll
        for (int kt = 0; kt < 16; ++kt) {
            const int kb = kt * 32 + lhi * 16;
            s16x8 wf = *reinterpret_cast<const s16x8*>(hw + l31 * 512 + (kb ^ ((l31 & 7) << 4)));
            s16x8 af = *reinterpret_cast<const s16x8*>(lds + act_off(wv * 32 + l31, kb));
            a = __builtin_amdgcn_mfma_f32_32x32x16_bf16(wf, af, a, 0, 0, 0);
        }
        if (lhi == 0) {   // channels 0..2 live in regs r=0,1,2 of the lhi=0 half
            const int p = pix0 + wv * 32 + l31;
            out[p * 3 + 0] = a[0] + bl[0];
            out[p * 3 + 1] = a[1] + bl[1];
            out[p * 3 + 2] = a[2] + bl[2];
        }
    }
}

extern "C" void kernel_launch(void* const* d_in, const int* in_sizes, int n_in,
                              void* d_out, int out_size, void* d_ws, size_t ws_size,
                              hipStream_t stream) {
    (void)in_sizes; (void)n_in; (void)d_ws; (void)ws_size; (void)out_size;
    const float* coords = (const float*)d_in[0];
    const float* w0 = (const float*)d_in[1];  const float* b0 = (const float*)d_in[2];
    const float* w1 = (const float*)d_in[3];  const float* b1 = (const float*)d_in[4];
    const float* w2 = (const float*)d_in[5];  const float* b2 = (const float*)d_in[6];
    const float* w3 = (const float*)d_in[7];  const float* b3 = (const float*)d_in[8];
    const float* w4 = (const float*)d_in[9];  const float* b4 = (const float*)d_in[10];
    const float* wl = (const float*)d_in[11]; const float* bl = (const float*)d_in[12];
    float* out = (float*)d_out;

    hipFuncSetAttribute((const void*)loe_fused,
                        hipFuncAttributeMaxDynamicSharedMemorySize, LDS_BYTES);

    loe_fused<<<dim3(NPIX / 256), dim3(NTHR), LDS_BYTES, stream>>>(
        coords, w0, b0, w1, b1, w2, b2, w3, b3, w4, b4, wl, bl, out);
}

// Round 4
// 188.409 us; speedup vs baseline: 2.1204x; 1.1772x over previous
//
#include <hip/hip_runtime.h>
#include <stdint.h>

typedef uint32_t u32;
typedef short s16x8 __attribute__((ext_vector_type(8)));
typedef float f32x16 __attribute__((ext_vector_type(16)));
typedef u32 u32x2 __attribute__((ext_vector_type(2)));
typedef u32 u32x4 __attribute__((ext_vector_type(4)));

#define NPIX   262144
#define HD     256
#define NTHR   512

#define ACT_BYTES  131072
#define WBUF_BYTES 16384
#define LDS_BYTES  (ACT_BYTES + 2 * WBUF_BYTES)   // 160 KiB exactly

// ---- pre-converted weight blob layout in d_ws (bytes) ----
#define B0_OFF  0u           // w0: 2 slice-images  (32 KB)
#define B1_OFF  32768u       // w1: 4 tiles x 128KB
#define B2_OFF  557056u      // w2: 16 tiles
#define B3_OFF  2654208u     // w3: 64 tiles
#define B4_OFF  11042816u    // w4: 256 tiles
#define BH_OFF  44597248u    // head image (16 KB)
#define BLOB_TOTAL 44613632u
// 16B-unit section bounds for the pre-pass flat index
#define F_W1 2048u
#define F_W2 34816u
#define F_W3 165888u
#define F_W4 690176u
#define F_WH 2787328u
#define F_END 2788352u       // = 10892 * 256

typedef __attribute__((address_space(3))) u32 as3_u32;
typedef __attribute__((address_space(1))) u32 as1_u32;

__device__ __forceinline__ void gload16(const void* g, void* l) {
    __builtin_amdgcn_global_load_lds((const as1_u32*)(uintptr_t)g,
                                     (as3_u32*)(u32)(uintptr_t)l, 16, 0, 0);
}

__device__ __forceinline__ u32 bfpair(float a, float b) {   // RTNE pack, known-correct
    u32 ua = __builtin_bit_cast(u32, a);
    u32 ub = __builtin_bit_cast(u32, b);
    ua = (ua + 0x7FFFu + ((ua >> 16) & 1u)) >> 16;
    ub = (ub + 0x7FFFu + ((ub >> 16) & 1u)) >> 16;
    return ua | (ub << 16);
}
// actA: row stride 512B, XOR-swizzle byte bits 4-6 by row&7
__device__ __forceinline__ u32 act_off(int row, int colByte) {
    return (u32)((row << 9) + (colByte ^ ((row & 7) << 4)));
}
// wbuf image: col stride 64B (32 k * 2B), XOR-swizzle byte bits 4-5 by (col>>1)&3
__device__ __forceinline__ u32 w_off32(int col, int kByte) {
    return (u32)((col << 6) + (kByte ^ (((col >> 1) & 3) << 4)));
}

// =================== pre-pass: f32 weights -> swizzled bf16 slice images ===================
extern "C" __global__ __launch_bounds__(256)
void loe_prepass(const float* __restrict__ w0, const float* __restrict__ w1,
                 const float* __restrict__ w2, const float* __restrict__ w3,
                 const float* __restrict__ w4, const float* __restrict__ wl,
                 char* __restrict__ ws)
{
    const u32 f = blockIdx.x * 256 + threadIdx.x;   // one 16B output chunk per thread
    if (f >= F_END) return;
    float v[8];
    char* dst;
    if (f < F_W1) {                                   // ---- w0 (K=54 padded to 64) ----
        const u32 s = f >> 10, r2 = f & 1023, col = r2 >> 2, kg = r2 & 3;
        const u32 k0 = s * 32 + kg * 8;
        #pragma unroll
        for (int j = 0; j < 8; ++j)
            v[j] = (k0 + j < 54) ? w0[(k0 + j) * HD + col] : 0.0f;
        dst = ws + B0_OFF + s * 16384 + w_off32(col, kg * 16);
    } else if (f < F_WH) {                            // ---- hidden layers ----
        const float* W; size_t boff; u32 fl;
        if (f < F_W2)      { W = w1; boff = B1_OFF; fl = f - F_W1; }
        else if (f < F_W3) { W = w2; boff = B2_OFF; fl = f - F_W2; }
        else if (f < F_W4) { W = w3; boff = B3_OFF; fl = f - F_W3; }
        else               { W = w4; boff = B4_OFF; fl = f - F_W4; }
        const u32 t = fl >> 13, r = fl & 8191, s = r >> 10, r2 = r & 1023;
        const u32 col = r2 >> 2, kg = r2 & 3;
        const u32 k0 = s * 32 + kg * 8;
        const float* src = W + (size_t)t * 65536 + (size_t)k0 * HD + col;
        #pragma unroll
        for (int j = 0; j < 8; ++j) v[j] = src[(size_t)j * HD];
        dst = ws + boff + (size_t)t * 131072 + s * 16384 + w_off32(col, kg * 16);
    } else {                                          // ---- head (3 ch padded to 32) ----
        const u32 fl = f - F_WH;
        const u32 col = fl >> 5, kg = fl & 31, k0 = kg * 8;
        #pragma unroll
        for (int j = 0; j < 8; ++j)
            v[j] = (col < 3) ? wl[col * HD + k0 + j] : 0.0f;
        dst = ws + BH_OFF + col * 512 + ((kg * 16) ^ ((col & 7) << 4));
    }
    u32x4 pk;
    pk.x = bfpair(v[0], v[1]); pk.y = bfpair(v[2], v[3]);
    pk.z = bfpair(v[4], v[5]); pk.w = bfpair(v[6], v[7]);
    *reinterpret_cast<u32x4*>(dst) = pk;
}

// =================== fused MLP, weights streamed from pre-converted blob ===================
extern "C" __global__ __launch_bounds__(NTHR, 2)
void loe_fused_pre(const float* __restrict__ coords,
                   const float* __restrict__ b0, const float* __restrict__ b1,
                   const float* __restrict__ b2, const float* __restrict__ b3,
                   const float* __restrict__ b4, const float* __restrict__ bl,
                   const char* __restrict__ blob,
                   float* __restrict__ out)
{
    extern __shared__ char lds[];
    char* wbufg = lds + ACT_BYTES;

    const int tid  = threadIdx.x;
    const int lane = tid & 63;
    const int wv   = tid >> 6;
    const int wr   = wv >> 2;
    const int wc   = wv & 3;
    const int l31  = lane & 31;
    const int lhi  = lane >> 5;

    const int bid  = (int)blockIdx.x;
    const int pb   = ((bid & 7) << 7) | (bid >> 3);   // bijective XCD swizzle
    const int pix0 = pb << 8;

    int g = 0;   // stage parity counter

    auto stage = [&](const char* src, int parity) {   // 16KB image -> wbuf[parity]
        const char* s0 = src + wv * 2048 + (size_t)lane * 16;
        char* d0 = wbufg + parity * WBUF_BYTES + wv * 2048;   // wave-uniform dest
        gload16(s0, d0);
        gload16(s0 + 1024, d0 + 1024);
    };

    const char* b0p = blob + B0_OFF;
    const char* b1p = blob + B1_OFF + (size_t)(pb >> 8) * 131072;
    const char* b2p = blob + B2_OFF + (size_t)(pb >> 6) * 131072;
    const char* b3p = blob + B3_OFF + (size_t)(pb >> 4) * 131072;
    const char* b4p = blob + B4_OFF + (size_t)(pb >> 2) * 131072;
    const char* bHp = blob + BH_OFF;

    stage(b0p, 0);    // layer-0 slice 0; completes under PE below

    // ---------------- positional encoding -> actA ----------------
    {
        const int p = tid >> 1;
        const int h = tid & 1;
        const float2 c2 = reinterpret_cast<const float2*>(coords)[pix0 + p];
        const float cf[2] = {c2.x, c2.y};
        #pragma unroll
        for (int u = 0; u < 32; u += 2) {
            float v[2];
            #pragma unroll
            for (int q = 0; q < 2; ++q) {
                const int c = h * 32 + u + q;
                float val;
                if (c < 2) val = cf[c];
                else if (c - 2 >= 52) val = 0.0f;
                else {
                    const int e = c - 2;
                    const float a = cf[(e >> 1) & 1] * (float)(1 << (e >> 2));
                    val = (e & 1) ? cospif(a) : sinpif(a);
                }
                v[q] = val;
            }
            *reinterpret_cast<u32*>(lds + act_off(p, (h * 32 + u) * 2)) = bfpair(v[0], v[1]);
        }
    }

    f32x16 acc[4][2];

    auto init_acc = [&](const float* Bias) {          // bias baked into accumulator
        #pragma unroll
        for (int ct = 0; ct < 2; ++ct)
            #pragma unroll
            for (int q = 0; q < 4; ++q) {
                const float4 bv = *reinterpret_cast<const float4*>(Bias + wc * 64 + ct * 32 + q * 8 + lhi * 4);
                #pragma unroll
                for (int pt = 0; pt < 4; ++pt) {
                    acc[pt][ct][q * 4 + 0] = bv.x; acc[pt][ct][q * 4 + 1] = bv.y;
                    acc[pt][ct][q * 4 + 2] = bv.z; acc[pt][ct][q * 4 + 3] = bv.w;
                }
            }
    };

    auto epilogue = [&]() {
        #pragma unroll
        for (int ct = 0; ct < 2; ++ct)
            #pragma unroll
            for (int q = 0; q < 4; ++q) {
                const int oc0 = wc * 64 + ct * 32 + q * 8 + lhi * 4;
                #pragma unroll
                for (int pt = 0; pt < 4; ++pt) {
                    const int p = wr * 128 + pt * 32 + l31;
                    float x[4];
                    #pragma unroll
                    for (int j = 0; j < 4; ++j) {
                        const float v = acc[pt][ct][q * 4 + j];
                        x[j] = fmaxf(v, 0.2f * v);    // LeakyReLU(0.2) == max(x, 0.2x)
                    }
                    u32x2 w2v;
                    w2v.x = bfpair(x[0], x[1]);
                    w2v.y = bfpair(x[2], x[3]);
                    *reinterpret_cast<u32x2*>(lds + act_off(p, oc0 * 2)) = w2v;
                }
            }
    };

    auto run_layer = [&](int S, const char* cur, const char* nxt, const float* Bias) {
        init_acc(Bias);
        for (int s = 0; s < S; ++s) {
            __syncthreads();                           // buf[g&1] ready (drains prior stage)
            const char* pf = (s + 1 < S) ? cur + (size_t)(s + 1) * 16384 : nxt;
            stage(pf, (g + 1) & 1);                    // overlaps with MFMA below
            const char* wbw = wbufg + (g & 1) * WBUF_BYTES;
            const int kbase = s * 64;
            #pragma unroll
            for (int kt = 0; kt < 2; ++kt) {
                const int kb = kt * 32 + lhi * 16;
                s16x8 wf[2], af[4];
                #pragma unroll
                for (int ct = 0; ct < 2; ++ct)
                    wf[ct] = *reinterpret_cast<const s16x8*>(wbw + w_off32(wc * 64 + ct * 32 + l31, kb));
                #pragma unroll
                for (int pt = 0; pt < 4; ++pt)
                    af[pt] = *reinterpret_cast<const s16x8*>(lds + act_off(wr * 128 + pt * 32 + l31, kbase + kb));
                #pragma unroll
                for (int pt = 0; pt < 4; ++pt)
                    #pragma unroll
                    for (int ct = 0; ct < 2; ++ct)
                        acc[pt][ct] = __builtin_amdgcn_mfma_f32_32x32x16_bf16(wf[ct], af[pt], acc[pt][ct], 0, 0, 0);
            }
            ++g;
        }
        __syncthreads();                               // act reads done before overwrite
        epilogue();
    };

    run_layer(2, b0p, b1p, b0);
    run_layer(8, b1p, b2p, b1);
    run_layer(8, b2p, b3p, b2);
    run_layer(8, b3p, b4p, b3);
    run_layer(8, b4p, bHp, b4);

    // ---------------- head ----------------
    __syncthreads();   // drains head image stage; epilogue-4 visible
    {
        const char* hw = wbufg + (g & 1) * WBUF_BYTES;
        f32x16 a;
        #pragma unroll
        for (int r = 0; r < 16; ++r) a[r] = 0.0f;
        #pragma unroll
        for (int kt = 0; kt < 16; ++kt) {
            const int kb = kt * 32 + lhi * 16;
            s16x8 wf = *reinterpret_cast<const s16x8*>(hw + l31 * 512 + (kb ^ ((l31 & 7) << 4)));
            s16x8 af = *reinterpret_cast<const s16x8*>(lds + act_off(wv * 32 + l31, kb));
            a = __builtin_amdgcn_mfma_f32_32x32x16_bf16(wf, af, a, 0, 0, 0);
        }
        if (lhi == 0) {
            const int p = pix0 + wv * 32 + l31;
            out[p * 3 + 0] = a[0] + bl[0];
            out[p * 3 + 1] = a[1] + bl[1];
            out[p * 3 + 2] = a[2] + bl[2];
        }
    }
}

// =================== fallback (r2 kernel, used only if ws too small) ===================
extern "C" __global__ __launch_bounds__(NTHR, 2)
void loe_fused_fb(const float* __restrict__ coords,
                  const float* __restrict__ w0, const float* __restrict__ b0,
                  const float* __restrict__ w1, const float* __restrict__ b1,
                  const float* __restrict__ w2, const float* __restrict__ b2,
                  const float* __restrict__ w3, const float* __restrict__ b3,
                  const float* __restrict__ w4, const float* __restrict__ b4,
                  const float* __restrict__ wl, const float* __restrict__ bl,
                  float* __restrict__ out)
{
    extern __shared__ char lds[];
    const int tid  = threadIdx.x;
    const int lane = tid & 63;
    const int wv   = tid >> 6;
    const int wr   = wv >> 2;
    const int wc   = wv & 3;
    const int l31  = lane & 31;
    const int lhi  = lane >> 5;
    const int bid  = (int)blockIdx.x;
    const int pb   = ((bid & 7) << 7) | (bid >> 3);
    const int pix0 = pb << 8;
    const int scol = tid & 255;
    const int kh   = tid >> 8;

    float st[16];
    auto load_plain = [&](const float* W, int s) {
        const float* src = W + (size_t)(s * 32 + kh * 16) * HD + scol;
        #pragma unroll
        for (int j = 0; j < 16; ++j) st[j] = src[(size_t)j * HD];
    };
    auto load_guard = [&](const float* W, int s) {
        #pragma unroll
        for (int j = 0; j < 16; ++j) {
            const int k = s * 32 + kh * 16 + j;
            st[j] = (k < 54) ? W[k * HD + scol] : 0.0f;
        }
    };
    load_guard(w0, 0);
    {
        const int p = tid >> 1;
        const int h = tid & 1;
        const float2 c2 = reinterpret_cast<const float2*>(coords)[pix0 + p];
        const float cf[2] = {c2.x, c2.y};
        #pragma unroll
        for (int u = 0; u < 32; u += 2) {
            float v[2];
            #pragma unroll
            for (int q = 0; q < 2; ++q) {
                const int c = h * 32 + u + q;
                float val;
                if (c < 2) val = cf[c];
                else if (c - 2 >= 52) val = 0.0f;
                else {
                    const int e = c - 2;
                    const float a = cf[(e >> 1) & 1] * (float)(1 << (e >> 2));
                    val = (e & 1) ? cospif(a) : sinpif(a);
                }
                v[q] = val;
            }
            *reinterpret_cast<u32*>(lds + act_off(p, (h * 32 + u) * 2)) = bfpair(v[0], v[1]);
        }
    }
    f32x16 acc[4][2];
    int g = 0;
    auto epilogue = [&](const float* Bias) {
        #pragma unroll
        for (int ct = 0; ct < 2; ++ct)
            #pragma unroll
            for (int q = 0; q < 4; ++q) {
                const int oc0 = wc * 64 + ct * 32 + q * 8 + lhi * 4;
                const float4 bv = *reinterpret_cast<const float4*>(Bias + oc0);
                const float bj[4] = {bv.x, bv.y, bv.z, bv.w};
                #pragma unroll
                for (int pt = 0; pt < 4; ++pt) {
                    const int p = wr * 128 + pt * 32 + l31;
                    float x[4];
                    #pragma unroll
                    for (int j = 0; j < 4; ++j) {
                        float v = acc[pt][ct][q * 4 + j] + bj[j];
                        x[j] = (v > 0.0f) ? v : 0.2f * v;
                    }
                    u32x2 wv2;
                    wv2.x = bfpair(x[0], x[1]);
                    wv2.y = bfpair(x[2], x[3]);
                    *reinterpret_cast<u32x2*>(lds + act_off(p, oc0 * 2)) = wv2;
                }
            }
    };
    auto run_layer = [&](int S, const float* Wcur, const float* Wnext,
                         const float* Bias, bool guard) {
        #pragma unroll
        for (int pt = 0; pt < 4; ++pt)
            #pragma unroll
            for (int ct = 0; ct < 2; ++ct)
                #pragma unroll
                for (int r = 0; r < 16; ++r) acc[pt][ct][r] = 0.0f;
        for (int s = 0; s < S; ++s) {
            char* wbw = lds + ACT_BYTES + ((g & 1) ? WBUF_BYTES : 0);
            u32x4 pk0, pk1;
            pk0.x = bfpair(st[0], st[1]);   pk0.y = bfpair(st[2], st[3]);
            pk0.z = bfpair(st[4], st[5]);   pk0.w = bfpair(st[6], st[7]);
            pk1.x = bfpair(st[8], st[9]);   pk1.y = bfpair(st[10], st[11]);
            pk1.z = bfpair(st[12], st[13]); pk1.w = bfpair(st[14], st[15]);
            *reinterpret_cast<u32x4*>(wbw + w_off32(scol, kh * 32))      = pk0;
            *reinterpret_cast<u32x4*>(wbw + w_off32(scol, kh * 32 + 16)) = pk1;
            if (s + 1 < S) { if (guard) load_guard(Wcur, s + 1); else load_plain(Wcur, s + 1); }
            else if (Wnext) load_plain(Wnext, 0);
            __syncthreads();
            const int kbase = s * 64;
            #pragma unroll
            for (int kt = 0; kt < 2; ++kt) {
                const int kb = kt * 32 + lhi * 16;
                s16x8 wf[2], af[4];
                #pragma unroll
                for (int ct = 0; ct < 2; ++ct)
                    wf[ct] = *reinterpret_cast<const s16x8*>(wbw + w_off32(wc * 64 + ct * 32 + l31, kb));
                #pragma unroll
                for (int pt = 0; pt < 4; ++pt)
                    af[pt] = *reinterpret_cast<const s16x8*>(lds + act_off(wr * 128 + pt * 32 + l31, kbase + kb));
                #pragma unroll
                for (int pt = 0; pt < 4; ++pt)
                    #pragma unroll
                    for (int ct = 0; ct < 2; ++ct)
                        acc[pt][ct] = __builtin_amdgcn_mfma_f32_32x32x16_bf16(wf[ct], af[pt], acc[pt][ct], 0, 0, 0);
            }
            ++g;
        }
        __syncthreads();
        epilogue(Bias);
    };
    const float* w1t = w1 + (size_t)(pb >> 8) * 65536;
    const float* w2t = w2 + (size_t)(pb >> 6) * 65536;
    const float* w3t = w3 + (size_t)(pb >> 4) * 65536;
    const float* w4t = w4 + (size_t)(pb >> 2) * 65536;
    run_layer(2, w0,  w1t, b0, true);
    run_layer(8, w1t, w2t, b1, false);
    run_layer(8, w2t, w3t, b2, false);
    run_layer(8, w3t, w4t, b3, false);
    run_layer(8, w4t, nullptr, b4, false);
    char* hw = lds + ACT_BYTES;
    #pragma unroll
    for (int rep = 0; rep < 2; ++rep) {
        const int task = rep * NTHR + tid;
        const int col  = task & 31;
        const int kg   = task >> 5;
        float v[8];
        #pragma unroll
        for (int j = 0; j < 8; ++j)
            v[j] = (col < 3) ? wl[col * HD + kg * 8 + j] : 0.0f;
        u32x4 pk;
        pk.x = bfpair(v[0], v[1]); pk.y = bfpair(v[2], v[3]);
        pk.z = bfpair(v[4], v[5]); pk.w = bfpair(v[6], v[7]);
        *reinterpret_cast<u32x4*>(hw + col * 512 + ((kg * 16) ^ ((col & 7) << 4))) = pk;
    }
    __syncthreads();
    {
        f32x16 a;
        #pragma unroll
        for (int r = 0; r < 16; ++r) a[r] = 0.0f;
        #pragma unroll
        for (int kt = 0; kt < 16; ++kt) {
            const int kb = kt * 32 + lhi * 16;
            s16x8 wf = *reinterpret_cast<const s16x8*>(hw + l31 * 512 + (kb ^ ((l31 & 7) << 4)));
            s16x8 af = *reinterpret_cast<const s16x8*>(lds + act_off(wv * 32 + l31, kb));
            a = __builtin_amdgcn_mfma_f32_32x32x16_bf16(wf, af, a, 0, 0, 0);
        }
        if (lhi == 0) {
            const int p = pix0 + wv * 32 + l31;
            out[p * 3 + 0] = a[0] + bl[0];
            out[p * 3 + 1] = a[1] + bl[1];
            out[p * 3 + 2] = a[2] + bl[2];
        }
    }
}

extern "C" void kernel_launch(void* const* d_in, const int* in_sizes, int n_in,
                              void* d_out, int out_size, void* d_ws, size_t ws_size,
                              hipStream_t stream) {
    (void)in_sizes; (void)n_in; (void)out_size;
    const float* coords = (const float*)d_in[0];
    const float* w0 = (const float*)d_in[1];  const float* b0 = (const float*)d_in[2];
    const float* w1 = (const float*)d_in[3];  const float* b1 = (const float*)d_in[4];
    const float* w2 = (const float*)d_in[5];  const float* b2 = (const float*)d_in[6];
    const float* w3 = (const float*)d_in[7];  const float* b3 = (const float*)d_in[8];
    const float* w4 = (const float*)d_in[9];  const float* b4 = (const float*)d_in[10];
    const float* wl = (const float*)d_in[11]; const float* bl = (const float*)d_in[12];
    float* out = (float*)d_out;

    if (ws_size >= (size_t)BLOB_TOTAL) {
        (void)hipFuncSetAttribute((const void*)loe_fused_pre,
                                  hipFuncAttributeMaxDynamicSharedMemorySize, LDS_BYTES);
        loe_prepass<<<dim3(F_END / 256), dim3(256), 0, stream>>>(
            w0, w1, w2, w3, w4, wl, (char*)d_ws);
        loe_fused_pre<<<dim3(NPIX / 256), dim3(NTHR), LDS_BYTES, stream>>>(
            coords, b0, b1, b2, b3, b4, bl, (const char*)d_ws, out);
    } else {
        (void)hipFuncSetAttribute((const void*)loe_fused_fb,
                                  hipFuncAttributeMaxDynamicSharedMemorySize, LDS_BYTES);
        loe_fused_fb<<<dim3(NPIX / 256), dim3(NTHR), LDS_BYTES, stream>>>(
            coords, w0, b0, w1, b1, w2, b2, w3, b3, w4, b4, wl, bl, out);
    }
}

// Round 6
// 185.845 us; speedup vs baseline: 2.1496x; 1.0138x over previous
//
#include <hip/hip_runtime.h>
#include <stdint.h>

typedef uint32_t u32;
typedef short s16x8 __attribute__((ext_vector_type(8)));
typedef float f32x16 __attribute__((ext_vector_type(16)));
typedef u32 u32x2 __attribute__((ext_vector_type(2)));
typedef u32 u32x4 __attribute__((ext_vector_type(4)));

#define NPIX   262144
#define HD     256

// ---------------- fused geometry ----------------
// 128 px per block, 256 threads (4 waves), act-only LDS = 64 KB -> 2 blocks/CU.
#define FTHR      256
#define PXB       128
#define NBLK      (NPIX / PXB)        // 2048
#define ACT_LDS   65536

// ---------------- weight blob (d_ws): per-lane MFMA A-fragment images ----------------
// hidden tile = [kk 16][fb 8][lane 64] x 16B = 128 KB; frag(lane) holds
// W[k = kk*16 + (lane>>5)*8 + j][f = fb*32 + (lane&31)], j=0..7, bf16.
#define B0_OFF  0u           // w0: [kk 4][fb 8][lane] = 32 KB (K=54 padded to 64)
#define B1_OFF  32768u       // w1: 4 tiles
#define B2_OFF  557056u      // w2: 16 tiles
#define B3_OFF  2654208u     // w3: 64 tiles
#define B4_OFF  11042816u    // w4: 256 tiles
#define BH_OFF  44597248u    // head: [kk 16][lane 64] = 16 KB (3 ch padded to 32)
#define BLOB_TOTAL 44613632u
#define F_W1 2048u
#define F_W2 34816u
#define F_W3 165888u
#define F_W4 690176u
#define F_WH 2787328u
#define F_END 2788352u

// fallback (r2-style) LDS layout
#define ACT_BYTES  131072
#define WBUF_BYTES 16384
#define FB_LDS     (ACT_BYTES + 2 * WBUF_BYTES)

__device__ __forceinline__ u32 bfpair(float a, float b) {   // RTNE pack (bit ops, proven)
    u32 ua = __builtin_bit_cast(u32, a);
    u32 ub = __builtin_bit_cast(u32, b);
    ua = (ua + 0x7FFFu + ((ua >> 16) & 1u)) >> 16;
    ub = (ub + 0x7FFFu + ((ub >> 16) & 1u)) >> 16;
    return ua | (ub << 16);
}
// act: row stride 512B; XOR-swizzle byte bits 4-8 by row&31 (bijective, 32-slot spread)
__device__ __forceinline__ u32 act_off(int row, int colByte) {
    return (u32)((row << 9) + (colByte ^ ((row & 31) << 4)));
}
// fallback wbuf: col stride 64B, swizzle bits 4-5 by (col>>1)&3
__device__ __forceinline__ u32 w_off32(int col, int kByte) {
    return (u32)((col << 6) + (kByte ^ (((col >> 1) & 3) << 4)));
}

// =================== pre-pass: f32 weights -> per-lane fragment blob ===================
extern "C" __global__ __launch_bounds__(256)
void loe_prepass(const float* __restrict__ w0, const float* __restrict__ w1,
                 const float* __restrict__ w2, const float* __restrict__ w3,
                 const float* __restrict__ w4, const float* __restrict__ wl,
                 char* __restrict__ ws)
{
    const u32 f = blockIdx.x * 256 + threadIdx.x;   // one 16B fragment chunk
    if (f >= F_END) return;
    float v[8];
    char* dst;
    if (f < F_W1) {                                   // ---- w0 ----
        const u32 kk = f >> 9, fb = (f >> 6) & 7, lane = f & 63;
        const u32 l31 = lane & 31, lhi = lane >> 5;
        const u32 k0 = kk * 16 + lhi * 8, col = fb * 32 + l31;
        #pragma unroll
        for (int j = 0; j < 8; ++j)
            v[j] = (k0 + j < 54) ? w0[(k0 + j) * HD + col] : 0.0f;
        dst = ws + B0_OFF + (size_t)f * 16;
    } else if (f < F_WH) {                            // ---- hidden layers ----
        const float* W; size_t boff; u32 fl;
        if (f < F_W2)      { W = w1; boff = B1_OFF; fl = f - F_W1; }
        else if (f < F_W3) { W = w2; boff = B2_OFF; fl = f - F_W2; }
        else if (f < F_W4) { W = w3; boff = B3_OFF; fl = f - F_W3; }
        else               { W = w4; boff = B4_OFF; fl = f - F_W4; }
        const u32 t = fl >> 13, c = fl & 8191;
        const u32 kk = c >> 9, fb = (c >> 6) & 7, lane = c & 63;
        const u32 l31 = lane & 31, lhi = lane >> 5;
        const u32 k0 = kk * 16 + lhi * 8, col = fb * 32 + l31;
        const float* src = W + (size_t)t * 65536 + (size_t)k0 * HD + col;
        #pragma unroll
        for (int j = 0; j < 8; ++j) v[j] = src[(size_t)j * HD];
        dst = ws + boff + (size_t)fl * 16;
    } else {                                          // ---- head ----
        const u32 fl = f - F_WH;
        const u32 kk = fl >> 6, lane = fl & 63;
        const u32 l31 = lane & 31, lhi = lane >> 5;
        const u32 k0 = kk * 16 + lhi * 8;
        #pragma unroll
        for (int j = 0; j < 8; ++j)
            v[j] = (l31 < 3) ? wl[l31 * HD + k0 + j] : 0.0f;
        dst = ws + BH_OFF + (size_t)fl * 16;
    }
    u32x4 pk;
    pk.x = bfpair(v[0], v[1]); pk.y = bfpair(v[2], v[3]);
    pk.z = bfpair(v[4], v[5]); pk.w = bfpair(v[6], v[7]);
    *reinterpret_cast<u32x4*>(dst) = pk;
}

// =================== fused MLP: W global->VGPR, act-only LDS ===================
extern "C" __global__ __launch_bounds__(FTHR, 2)
void loe_fused_pre(const float* __restrict__ coords,
                   const float* __restrict__ b0, const float* __restrict__ b1,
                   const float* __restrict__ b2, const float* __restrict__ b3,
                   const float* __restrict__ b4, const float* __restrict__ bl,
                   const char* __restrict__ blob,
                   float* __restrict__ out)
{
    extern __shared__ char lds[];

    const int tid  = threadIdx.x;
    const int lane = tid & 63;
    const int wv   = tid >> 6;      // wave 0..3 = feature quarter (and head px group)
    const int l31  = lane & 31;
    const int lhi  = lane >> 5;

    const int bid  = (int)blockIdx.x;
    const int pb   = ((bid & 7) << 8) | (bid >> 3);   // bijective XCD swizzle (2048 = 8*256)
    const int pix0 = pb << 7;

    // ---------------- positional encoding -> act[128 px][64 cols] ----------------
    {
        const int p = tid >> 1;
        const int h = tid & 1;
        const float2 c2 = reinterpret_cast<const float2*>(coords)[pix0 + p];
        const float cf[2] = {c2.x, c2.y};
        #pragma unroll
        for (int u = 0; u < 32; u += 2) {
            float v[2];
            #pragma unroll
            for (int q = 0; q < 2; ++q) {
                const int c = h * 32 + u + q;
                float val;
                if (c < 2) val = cf[c];
                else if (c - 2 >= 52) val = 0.0f;
                else {
                    const int e = c - 2;
                    const float a = cf[(e >> 1) & 1] * (float)(1 << (e >> 2));  // exact pow2 scale
                    val = (e & 1) ? cospif(a) : sinpif(a);     // proven-correct path (r1-r4)
                }
                v[q] = val;
            }
            *reinterpret_cast<u32*>(lds + act_off(p, (h * 32 + u) * 2)) = bfpair(v[0], v[1]);
        }
    }

    f32x16 acc[4][2];                 // acc[px-block][f-block]; D row=feature, col=px
    const u32 swz = (u32)(l31 << 4);
    u32 abase[4];
    #pragma unroll
    for (int pt = 0; pt < 4; ++pt) abase[pt] = (u32)((pt * 32 + l31) << 9);

    auto init_acc = [&](const float* Bias) {
        #pragma unroll
        for (int ct = 0; ct < 2; ++ct)
            #pragma unroll
            for (int q = 0; q < 4; ++q) {
                const float4 bv = *reinterpret_cast<const float4*>(Bias + wv * 64 + ct * 32 + q * 8 + lhi * 4);
                #pragma unroll
                for (int pt = 0; pt < 4; ++pt) {
                    acc[pt][ct][q * 4 + 0] = bv.x; acc[pt][ct][q * 4 + 1] = bv.y;
                    acc[pt][ct][q * 4 + 2] = bv.z; acc[pt][ct][q * 4 + 3] = bv.w;
                }
            }
    };

    auto epilogue = [&]() {           // LeakyReLU -> bf16 -> act LDS
        #pragma unroll
        for (int ct = 0; ct < 2; ++ct)
            #pragma unroll
            for (int q = 0; q < 4; ++q) {
                const int oc0 = wv * 64 + ct * 32 + q * 8 + lhi * 4;
                #pragma unroll
                for (int pt = 0; pt < 4; ++pt) {
                    float x[4];
                    #pragma unroll
                    for (int j = 0; j < 4; ++j) {
                        const float v = acc[pt][ct][q * 4 + j];
                        x[j] = fmaxf(v, 0.2f * v);
                    }
                    u32x2 wo;
                    wo.x = bfpair(x[0], x[1]);
                    wo.y = bfpair(x[2], x[3]);
                    *reinterpret_cast<u32x2*>(lds + act_off(pt * 32 + l31, oc0 * 2)) = wo;
                }
            }
    };

    // one layer: KK k-chunks of 16; W fragments from blob, depth-1 pipelined
    auto run_layer = [&](int KK, const char* wbase, const float* Bias) {
        init_acc(Bias);
        __syncthreads();              // prior act writes visible
        const char* f0 = wbase + (size_t)(wv * 2) * 1024 + (size_t)lane * 16;
        u32x4 wA = *reinterpret_cast<const u32x4*>(f0);
        u32x4 wB = *reinterpret_cast<const u32x4*>(f0 + 1024);
        #pragma unroll 4
        for (int kk = 0; kk < KK; ++kk) {
            const int nk = (kk + 1 < KK) ? kk + 1 : kk;
            const u32x4 nA = *reinterpret_cast<const u32x4*>(f0 + (size_t)nk * 8192);
            const u32x4 nB = *reinterpret_cast<const u32x4*>(f0 + (size_t)nk * 8192 + 1024);
            const u32 cb = (u32)(kk * 32 + lhi * 16) ^ swz;
            s16x8 af[4];
            #pragma unroll
            for (int pt = 0; pt < 4; ++pt)
                af[pt] = *reinterpret_cast<const s16x8*>(lds + abase[pt] + cb);
            const s16x8 a = __builtin_bit_cast(s16x8, wA);
            const s16x8 b = __builtin_bit_cast(s16x8, wB);
            #pragma unroll
            for (int pt = 0; pt < 4; ++pt)
                acc[pt][0] = __builtin_amdgcn_mfma_f32_32x32x16_bf16(a, af[pt], acc[pt][0], 0, 0, 0);
            #pragma unroll
            for (int pt = 0; pt < 4; ++pt)
                acc[pt][1] = __builtin_amdgcn_mfma_f32_32x32x16_bf16(b, af[pt], acc[pt][1], 0, 0, 0);
            wA = nA; wB = nB;
        }
        __syncthreads();              // all act reads done before overwrite
        epilogue();
    };

    const char* b0p = blob + B0_OFF;
    const char* b1p = blob + B1_OFF + (size_t)(pb >> 9) * 131072;
    const char* b2p = blob + B2_OFF + (size_t)(pb >> 7) * 131072;
    const char* b3p = blob + B3_OFF + (size_t)(pb >> 5) * 131072;
    const char* b4p = blob + B4_OFF + (size_t)(pb >> 3) * 131072;
    const char* bHp = blob + BH_OFF;

    run_layer(4,  b0p, b0);
    run_layer(16, b1p, b1);
    run_layer(16, b2p, b2);
    run_layer(16, b3p, b3);
    run_layer(16, b4p, b4);

    // ---------------- head: wave wv -> px wv*32..+32 ----------------
    __syncthreads();
    {
        f32x16 a;
        #pragma unroll
        for (int r = 0; r < 16; ++r) a[r] = 0.0f;
        const u32 hrow = (u32)((wv * 32 + l31) << 9);
        #pragma unroll 4
        for (int kk = 0; kk < 16; ++kk) {
            const u32x4 wh = *reinterpret_cast<const u32x4*>(bHp + (size_t)kk * 1024 + (size_t)lane * 16);
            const u32 cb = (u32)(kk * 32 + lhi * 16) ^ swz;
            const s16x8 af = *reinterpret_cast<const s16x8*>(lds + hrow + cb);
            a = __builtin_amdgcn_mfma_f32_32x32x16_bf16(__builtin_bit_cast(s16x8, wh), af, a, 0, 0, 0);
        }
        if (lhi == 0) {
            const int p = pix0 + wv * 32 + l31;
            out[p * 3 + 0] = a[0] + bl[0];
            out[p * 3 + 1] = a[1] + bl[1];
            out[p * 3 + 2] = a[2] + bl[2];
        }
    }
}

// =================== fallback (r2-style, used only if ws too small) ===================
extern "C" __global__ __launch_bounds__(512, 2)
void loe_fused_fb(const float* __restrict__ coords,
                  const float* __restrict__ w0, const float* __restrict__ b0,
                  const float* __restrict__ w1, const float* __restrict__ b1,
                  const float* __restrict__ w2, const float* __restrict__ b2,
                  const float* __restrict__ w3, const float* __restrict__ b3,
                  const float* __restrict__ w4, const float* __restrict__ b4,
                  const float* __restrict__ wl, const float* __restrict__ bl,
                  float* __restrict__ out)
{
    extern __shared__ char lds[];
    const int tid  = threadIdx.x;
    const int lane = tid & 63;
    const int wv   = tid >> 6;
    const int wr   = wv >> 2;
    const int wc   = wv & 3;
    const int l31  = lane & 31;
    const int lhi  = lane >> 5;
    const int bid  = (int)blockIdx.x;
    const int pb   = ((bid & 7) << 7) | (bid >> 3);
    const int pix0 = pb << 8;
    const int scol = tid & 255;
    const int kh   = tid >> 8;

    float st[16];
    auto load_plain = [&](const float* W, int s) {
        const float* src = W + (size_t)(s * 32 + kh * 16) * HD + scol;
        #pragma unroll
        for (int j = 0; j < 16; ++j) st[j] = src[(size_t)j * HD];
    };
    auto load_guard = [&](const float* W, int s) {
        #pragma unroll
        for (int j = 0; j < 16; ++j) {
            const int k = s * 32 + kh * 16 + j;
            st[j] = (k < 54) ? W[k * HD + scol] : 0.0f;
        }
    };
    load_guard(w0, 0);
    {
        const int p = tid >> 1;
        const int h = tid & 1;
        const float2 c2 = reinterpret_cast<const float2*>(coords)[pix0 + p];
        const float cf[2] = {c2.x, c2.y};
        #pragma unroll
        for (int u = 0; u < 32; u += 2) {
            float v[2];
            #pragma unroll
            for (int q = 0; q < 2; ++q) {
                const int c = h * 32 + u + q;
                float val;
                if (c < 2) val = cf[c];
                else if (c - 2 >= 52) val = 0.0f;
                else {
                    const int e = c - 2;
                    const float a = cf[(e >> 1) & 1] * (float)(1 << (e >> 2));
                    val = (e & 1) ? cospif(a) : sinpif(a);
                }
                v[q] = val;
            }
            *reinterpret_cast<u32*>(lds + act_off(p, (h * 32 + u) * 2)) = bfpair(v[0], v[1]);
        }
    }
    f32x16 acc[4][2];
    int g = 0;
    auto epilogue = [&](const float* Bias) {
        #pragma unroll
        for (int ct = 0; ct < 2; ++ct)
            #pragma unroll
            for (int q = 0; q < 4; ++q) {
                const int oc0 = wc * 64 + ct * 32 + q * 8 + lhi * 4;
                const float4 bv = *reinterpret_cast<const float4*>(Bias + oc0);
                const float bj[4] = {bv.x, bv.y, bv.z, bv.w};
                #pragma unroll
                for (int pt = 0; pt < 4; ++pt) {
                    const int p = wr * 128 + pt * 32 + l31;
                    float x[4];
                    #pragma unroll
                    for (int j = 0; j < 4; ++j) {
                        float v = acc[pt][ct][q * 4 + j] + bj[j];
                        x[j] = (v > 0.0f) ? v : 0.2f * v;
                    }
                    u32x2 wv2;
                    wv2.x = bfpair(x[0], x[1]);
                    wv2.y = bfpair(x[2], x[3]);
                    *reinterpret_cast<u32x2*>(lds + act_off(p, oc0 * 2)) = wv2;
                }
            }
    };
    auto run_layer = [&](int S, const float* Wcur, const float* Wnext,
                         const float* Bias, bool guard) {
        #pragma unroll
        for (int pt = 0; pt < 4; ++pt)
            #pragma unroll
            for (int ct = 0; ct < 2; ++ct)
                #pragma unroll
                for (int r = 0; r < 16; ++r) acc[pt][ct][r] = 0.0f;
        for (int s = 0; s < S; ++s) {
            char* wbw = lds + ACT_BYTES + ((g & 1) ? WBUF_BYTES : 0);
            u32x4 pk0, pk1;
            pk0.x = bfpair(st[0], st[1]);   pk0.y = bfpair(st[2], st[3]);
            pk0.z = bfpair(st[4], st[5]);   pk0.w = bfpair(st[6], st[7]);
            pk1.x = bfpair(st[8], st[9]);   pk1.y = bfpair(st[10], st[11]);
            pk1.z = bfpair(st[12], st[13]); pk1.w = bfpair(st[14], st[15]);
            *reinterpret_cast<u32x4*>(wbw + w_off32(scol, kh * 32))      = pk0;
            *reinterpret_cast<u32x4*>(wbw + w_off32(scol, kh * 32 + 16)) = pk1;
            if (s + 1 < S) { if (guard) load_guard(Wcur, s + 1); else load_plain(Wcur, s + 1); }
            else if (Wnext) load_plain(Wnext, 0);
            __syncthreads();
            #pragma unroll
            for (int kt = 0; kt < 2; ++kt) {
                const int kb = kt * 32 + lhi * 16;
                s16x8 wf[2], af[4];
                #pragma unroll
                for (int ct = 0; ct < 2; ++ct)
                    wf[ct] = *reinterpret_cast<const s16x8*>(wbw + w_off32(wc * 64 + ct * 32 + l31, kb));
                #pragma unroll
                for (int pt = 0; pt < 4; ++pt)
                    af[pt] = *reinterpret_cast<const s16x8*>(lds + act_off(wr * 128 + pt * 32 + l31, s * 64 + kb));
                #pragma unroll
                for (int pt = 0; pt < 4; ++pt)
                    #pragma unroll
                    for (int ct = 0; ct < 2; ++ct)
                        acc[pt][ct] = __builtin_amdgcn_mfma_f32_32x32x16_bf16(wf[ct], af[pt], acc[pt][ct], 0, 0, 0);
            }
            ++g;
            __syncthreads();
        }
        epilogue(Bias);
        __syncthreads();
    };
    const float* w1t = w1 + (size_t)(pb >> 8) * 65536;
    const float* w2t = w2 + (size_t)(pb >> 6) * 65536;
    const float* w3t = w3 + (size_t)(pb >> 4) * 65536;
    const float* w4t = w4 + (size_t)(pb >> 2) * 65536;
    __syncthreads();
    run_layer(2, w0,  w1t, b0, true);
    run_layer(8, w1t, w2t, b1, false);
    run_layer(8, w2t, w3t, b2, false);
    run_layer(8, w3t, w4t, b3, false);
    run_layer(8, w4t, nullptr, b4, false);
    char* hw = lds + ACT_BYTES;
    #pragma unroll
    for (int rep = 0; rep < 2; ++rep) {
        const int task = rep * 512 + tid;
        const int col  = task & 31;
        const int kg   = task >> 5;
        float v[8];
        #pragma unroll
        for (int j = 0; j < 8; ++j)
            v[j] = (col < 3) ? wl[col * HD + kg * 8 + j] : 0.0f;
        u32x4 pk;
        pk.x = bfpair(v[0], v[1]); pk.y = bfpair(v[2], v[3]);
        pk.z = bfpair(v[4], v[5]); pk.w = bfpair(v[6], v[7]);
        *reinterpret_cast<u32x4*>(hw + col * 512 + ((kg * 16) ^ ((col & 7) << 4))) = pk;
    }
    __syncthreads();
    {
        f32x16 a;
        #pragma unroll
        for (int r = 0; r < 16; ++r) a[r] = 0.0f;
        #pragma unroll
        for (int kt = 0; kt < 16; ++kt) {
            const int kb = kt * 32 + lhi * 16;
            s16x8 wf = *reinterpret_cast<const s16x8*>(hw + l31 * 512 + (kb ^ ((l31 & 7) << 4)));
            s16x8 af = *reinterpret_cast<const s16x8*>(lds + act_off(wv * 32 + l31, kb));
            a = __builtin_amdgcn_mfma_f32_32x32x16_bf16(wf, af, a, 0, 0, 0);
        }
        if (lhi == 0) {
            const int p = pix0 + wv * 32 + l31;
            out[p * 3 + 0] = a[0] + bl[0];
            out[p * 3 + 1] = a[1] + bl[1];
            out[p * 3 + 2] = a[2] + bl[2];
        }
    }
}

extern "C" void kernel_launch(void* const* d_in, const int* in_sizes, int n_in,
                              void* d_out, int out_size, void* d_ws, size_t ws_size,
                              hipStream_t stream) {
    (void)in_sizes; (void)n_in; (void)out_size;
    const float* coords = (const float*)d_in[0];
    const float* w0 = (const float*)d_in[1];  const float* b0 = (const float*)d_in[2];
    const float* w1 = (const float*)d_in[3];  const float* b1 = (const float*)d_in[4];
    const float* w2 = (const float*)d_in[5];  const float* b2 = (const float*)d_in[6];
    const float* w3 = (const float*)d_in[7];  const float* b3 = (const float*)d_in[8];
    const float* w4 = (const float*)d_in[9];  const float* b4 = (const float*)d_in[10];
    const float* wl = (const float*)d_in[11]; const float* bl = (const float*)d_in[12];
    float* out = (float*)d_out;

    if (ws_size >= (size_t)BLOB_TOTAL) {
        (void)hipFuncSetAttribute((const void*)loe_fused_pre,
                                  hipFuncAttributeMaxDynamicSharedMemorySize, ACT_LDS);
        loe_prepass<<<dim3((F_END + 255) / 256), dim3(256), 0, stream>>>(
            w0, w1, w2, w3, w4, wl, (char*)d_ws);
        loe_fused_pre<<<dim3(NBLK), dim3(FTHR), ACT_LDS, stream>>>(
            coords, b0, b1, b2, b3, b4, bl, (const char*)d_ws, out);
    } else {
        (void)hipFuncSetAttribute((const void*)loe_fused_fb,
                                  hipFuncAttributeMaxDynamicSharedMemorySize, FB_LDS);
        loe_fused_fb<<<dim3(NPIX / 256), dim3(512), FB_LDS, stream>>>(
            coords, w0, b0, w1, b1, w2, b2, w3, b3, w4, b4, wl, bl, out);
    }
}